// Round 9
// baseline (1017.096 us; speedup 1.0000x reference)
//
#include <hip/hip_runtime.h>
#include <math.h>

// ---------------------------------------------------------------------------
// GP posterior mean:
//   k_outer : R18: half-grid v (conj-symmetric). R19: col-phase LDS layout
//     j-contiguous so h2 loads are 4xb128. R22: launch_bounds back to
//     (256,2) — R20's (256,4) capped VGPR at 128 and regressed non-cg
//     time by ~16us (marginal spill).
//   k_reduce: R21: exact grid (272 blocks) + explicit f-branch guard
//     (R18's unguarded else raced pv via OOB rvec writes).
//   k_cg_solve: R22: wave-synchronous row-phase fusion — wave w owns rows
//     4w..4w+3 end-to-end, so {scatter+rowA+rowB} and {i_rowB+invRowA+Ap}
//     each run barrier-free within a wave (same-wave DS ops are in-order;
//     wave_barrier() pins compiler order). 8 -> 6 barriers/iter.
//     R19: fp32 CG state (540us verified). R17: Vf REAL fp32, 1/16384
//     folded. R16: local-const bfly16 twiddles; i_colA half store.
//     R14: CG-state remap + fused scatter/rowA + i_rowA/Ap.
//     R15 lesson: no register-array hoists (scratch spills at 64 VGPR).
//   k_eval  : R20: 256-thread blocks. R17 fp64 recurrences, 4 sincospi.
// ---------------------------------------------------------------------------

typedef float f2 __attribute__((ext_vector_type(2)));
#define PB 16
#define RS 137          // Z row stride in f2 (8 blocks x 17)

__device__ inline f2 f2s(float s) { return (f2){s, s}; }
__device__ inline f2 cmulf(f2 a, f2 b) {   // a*b
    return (f2){a.x * b.x - a.y * b.y, a.x * b.y + a.y * b.x};
}
__device__ inline f2 cmulcf(f2 a, f2 b) {  // a*conj(b)
    return (f2){a.x * b.x + a.y * b.y, a.y * b.x - a.x * b.y};
}
__device__ inline int cpad(int c) { return (c >> 4) * 17 + (c & 15); }

// exp(i*pi*x*m) with fp64 angle reduction, scaled
__device__ inline f2 phasef(float xv, float m, float scale) {
    double ang = (double)xv * (double)m;
    double r = ang - 2.0 * rint(ang * 0.5);
    float sn, cs;
    sincospif((float)r, &sn, &cs);
    return (f2){cs * scale, sn * scale};
}

// ---------------------------------------------------------------------------
// k_outer: v-part computes HALF grid (rows p1=0..63, cols p2=-63..63).
// LDS layout: hs[p][0..63] = row phases (p1 = t).
//             hs[p][64 + 8*(cc&15) + (cc>>4)] = col phase cc (j-contiguous
//             per tx so h2 loads are 4xb128). cc=127 slot is zero.
// ---------------------------------------------------------------------------
__global__ __launch_bounds__(256, 2) void k_outer(const float* __restrict__ x,
                                                  const float* __restrict__ y,
                                                  float* __restrict__ pv,
                                                  float* __restrict__ pf,
                                                  int N, int cv, int cf)
{
    __shared__ f2 hs[PB][256];
    __shared__ float xs0[PB], xs1[PB], ys[PB];

    int bx = blockIdx.x;
    int t  = threadIdx.x;
    int ty = t >> 4, tx = t & 15;

    if (bx < cv) {
        int CP = (N + cv - 1) / cv;
        int n0 = bx * CP, n1 = min(N, n0 + CP);

        f2 acc[4][8];
        #pragma unroll
        for (int i = 0; i < 4; ++i)
            #pragma unroll
            for (int j = 0; j < 8; ++j) acc[i][j] = (f2){0.f, 0.f};

        for (int s = n0; s < n1; s += PB) {
            int cnt = min(PB, n1 - s);
            __syncthreads();
            if (t < cnt) {
                xs0[t] = x[2 * (s + t)];
                xs1[t] = x[2 * (s + t) + 1];
            }
            __syncthreads();
            for (int p = 0; p < cnt; ++p) {
                if (t < 192) {
                    if (t < 64) {
                        hs[p][t] = phasef(xs0[p], (float)t, 1.f);       // p1 = t
                    } else {
                        int cc = t - 64;                                 // 0..127
                        f2 g = (cc == 127) ? (f2){0.f, 0.f}
                                           : phasef(xs1[p], (float)(cc - 63), 1.f);
                        hs[p][64 + 8 * (cc & 15) + (cc >> 4)] = g;
                    }
                }
            }
            __syncthreads();
            for (int p = 0; p < cnt; ++p) {
                f2 h1[4], h2[8], h2s[8];
                #pragma unroll
                for (int i = 0; i < 4; ++i) h1[i] = hs[p][ty * 4 + i];
                #pragma unroll
                for (int j = 0; j < 8; ++j) {
                    f2 b = hs[p][64 + 8 * tx + j];                       // contiguous
                    h2[j] = b;
                    h2s[j] = (f2){-b.y, b.x};
                }
                #pragma unroll
                for (int i = 0; i < 4; ++i)
                    #pragma unroll
                    for (int j = 0; j < 8; ++j) {
                        acc[i][j] = acc[i][j] + f2s(h1[i].x) * h2[j];
                        acc[i][j] = acc[i][j] + f2s(h1[i].y) * h2s[j];
                    }
            }
        }
        __syncthreads();
        f2* out = (f2*)pv + (size_t)bx * 8192;           // 64x128 f2 = 64KB
        #pragma unroll
        for (int i = 0; i < 4; ++i) {
            int a = ty * 4 + i;
            #pragma unroll
            for (int j = 0; j < 8; ++j)
                out[a * 128 + tx + 16 * j] = acc[i][j];
        }
    } else {
        int chunk = bx - cv;
        int CP = (N + cf - 1) / cf;
        int n0 = chunk * CP, n1 = min(N, n0 + CP);

        f2 acc[4][4];
        #pragma unroll
        for (int i = 0; i < 4; ++i)
            #pragma unroll
            for (int j = 0; j < 4; ++j) acc[i][j] = (f2){0.f, 0.f};

        for (int s = n0; s < n1; s += PB) {
            int cnt = min(PB, n1 - s);
            __syncthreads();
            if (t < cnt) {
                xs0[t] = x[2 * (s + t)];
                xs1[t] = x[2 * (s + t) + 1];
                ys[t]  = y[s + t];
            }
            __syncthreads();
            for (int p2 = 0; p2 < cnt; p2 += 2) {
                int p = p2 + (t >> 7);
                int c = t & 127;
                if (p < cnt) {
                    f2 g;
                    if (c < 64) g = phasef(xs0[p], (float)(32 - c), ys[p]);
                    else        g = phasef(xs1[p], (float)(32 - (c - 64)), 1.f);
                    hs[p][c] = g;
                }
            }
            __syncthreads();
            for (int p = 0; p < cnt; ++p) {
                f2 h1[4], h2[4], h2s[4];
                #pragma unroll
                for (int i = 0; i < 4; ++i) h1[i] = hs[p][ty * 4 + i];
                #pragma unroll
                for (int j = 0; j < 4; ++j) {
                    f2 b = hs[p][64 + tx + 16 * j];
                    h2[j] = b;
                    h2s[j] = (f2){-b.y, b.x};
                }
                #pragma unroll
                for (int i = 0; i < 4; ++i)
                    #pragma unroll
                    for (int j = 0; j < 4; ++j) {
                        acc[i][j] = acc[i][j] + f2s(h1[i].x) * h2[j];
                        acc[i][j] = acc[i][j] + f2s(h1[i].y) * h2s[j];
                    }
            }
        }
        __syncthreads();
        f2* out = (f2*)pf + (size_t)chunk * 4096;
        #pragma unroll
        for (int i = 0; i < 4; ++i) {
            int a = ty * 4 + i;
            #pragma unroll
            for (int j = 0; j < 4; ++j)
                out[a * 64 + tx + 16 * j] = acc[i][j];
        }
    }
}

// ---------------------------------------------------------------------------
// k_reduce: R21. Grid sized EXACTLY: 65536 v-threads + 4096 f-threads =
// 69632 = 272 blocks, plus explicit guard.
//   direct: q1 = p1,        q2 = (b+65)&127,  value (sx,  sy)
//   mirror: q1 = 128-p1,    q2 = (63-b)&127,  value (sx, -sy)   [p1>0 only]
// ---------------------------------------------------------------------------
__global__ __launch_bounds__(256) void k_reduce(const float* __restrict__ pv,
                                                const float* __restrict__ pf,
                                                const float* __restrict__ wsv,
                                                float* __restrict__ vcf,
                                                double2* __restrict__ rvec,
                                                int cv, int cf)
{
    int id = blockIdx.x * 256 + threadIdx.x;
    if (id < 65536) {
        int e = id >> 3, sl = id & 7;        // e: p1 = e>>7 (0..63), b = e&127
        int cn = cv >> 3;
        const float* src = pv + (size_t)e * 2 + (size_t)(sl * cn) * 16384;
        float sx = 0.f, sy = 0.f;
        for (int c = 0; c < cn; ++c) { sx += src[0]; sy += src[1]; src += 16384; }
        int p1 = e >> 7, b = e & 127;
        int q2 = (b + 65) & 127;
        atomicAdd(&vcf[(p1 * 128 + q2) * 2],     sx);
        atomicAdd(&vcf[(p1 * 128 + q2) * 2 + 1], sy);
        if (p1 > 0) {
            int q1m = 128 - p1, q2m = (63 - b) & 127;
            atomicAdd(&vcf[(q1m * 128 + q2m) * 2],     sx);
            atomicAdd(&vcf[(q1m * 128 + q2m) * 2 + 1], -sy);
        }
    } else {
        int e = id - 65536;
        if (e < 4096) {                      // R21: explicit bound
            const float* s2p = pf + (size_t)e * 2;
            double fx = 0.0, fy2 = 0.0;
            for (int c = 0; c < cf; ++c) { fx += (double)s2p[0]; fy2 += (double)s2p[1]; s2p += 8192; }
            double w = (double)wsv[e];
            rvec[e] = make_double2(w * fx, w * fy2);
        }
    }
}

// ---------------------------------------------------------------------------
// Fused-stage FFT passes, STATIC register indexing only.
// Z[r*RS + cpad(c)], RS=137. tw[t] = exp(-i*pi*t/64) = W_128^t.
// bfly16 twiddles are lane-uniform -> LOCAL const tables (SROA-folded).
// ---------------------------------------------------------------------------
#define TC1 0.92387953251128676f   // cos(pi/8)
#define TS1 0.38268343236508977f   // sin(pi/8)
#define TSQ 0.70710678118654752f   // sqrt(2)/2

__device__ inline void bflyA_fwd(f2* L, const f2* tw, int b) {
    #pragma unroll
    for (int s = 0; s < 4; ++s) {                    // h=64
        f2 u0 = L[s], v0 = L[s + 4];
        L[s] = u0 + v0;
        L[s + 4] = cmulf(u0 - v0, tw[b + 16 * s]);
    }
    const int ss[4] = {0, 1, 4, 5};
    #pragma unroll
    for (int q = 0; q < 4; ++q) {                    // h=32
        int s = ss[q];
        f2 u0 = L[s], v0 = L[s + 2];
        L[s] = u0 + v0;
        L[s + 2] = cmulf(u0 - v0, tw[2 * b + 32 * (s & 1)]);
    }
    #pragma unroll
    for (int s = 0; s < 8; s += 2) {                 // h=16
        f2 u0 = L[s], v0 = L[s + 1];
        L[s] = u0 + v0;
        L[s + 1] = cmulf(u0 - v0, tw[4 * b]);
    }
}
__device__ inline void bflyA_inv(f2* L, const f2* tw, int b) {
    #pragma unroll
    for (int s = 0; s < 8; s += 2) {                 // h=16
        f2 u0 = L[s];
        f2 vw = cmulcf(L[s + 1], tw[4 * b]);
        L[s] = u0 + vw; L[s + 1] = u0 - vw;
    }
    const int ss[4] = {0, 1, 4, 5};
    #pragma unroll
    for (int q = 0; q < 4; ++q) {                    // h=32
        int s = ss[q];
        f2 u0 = L[s];
        f2 vw = cmulcf(L[s + 2], tw[2 * b + 32 * (s & 1)]);
        L[s] = u0 + vw; L[s + 2] = u0 - vw;
    }
    #pragma unroll
    for (int s = 0; s < 4; ++s) {                    // h=64
        f2 u0 = L[s];
        f2 vw = cmulcf(L[s + 4], tw[b + 16 * s]);
        L[s] = u0 + vw; L[s + 4] = u0 - vw;
    }
}
__device__ inline void bfly16_fwd(f2* M) {
    const float c8x[8]  = {1.f, TC1, TSQ, TS1, 0.f, -TS1, -TSQ, -TC1};
    const float c8y[8]  = {0.f, -TS1, -TSQ, -TC1, -1.f, -TC1, -TSQ, -TS1};
    const float c16x[4] = {1.f, TSQ, 0.f, -TSQ};
    const float c16y[4] = {0.f, -TSQ, -1.f, -TSQ};
    #pragma unroll
    for (int s = 0; s < 8; ++s) {                    // h=8
        f2 u0 = M[s], v0 = M[s + 8];
        M[s] = u0 + v0;
        M[s + 8] = cmulf(u0 - v0, (f2){c8x[s], c8y[s]});
    }
    #pragma unroll
    for (int q = 0; q < 8; ++q) {                    // h=4
        int s = (q & 3) + 8 * (q >> 2);
        f2 u0 = M[s], v0 = M[s + 4];
        M[s] = u0 + v0;
        M[s + 4] = cmulf(u0 - v0, (f2){c16x[s & 3], c16y[s & 3]});
    }
    #pragma unroll
    for (int q = 0; q < 8; ++q) {                    // h=2
        int s = (q & 1) + 4 * (q >> 1);
        f2 u0 = M[s], v0 = M[s + 2];
        M[s] = u0 + v0;
        f2 d = u0 - v0;
        M[s + 2] = (s & 1) ? (f2){d.y, -d.x} : d;    // * (0,-1) or * 1
    }
    #pragma unroll
    for (int s = 0; s < 16; s += 2) {                // h=1
        f2 u0 = M[s], v0 = M[s + 1];
        M[s] = u0 + v0; M[s + 1] = u0 - v0;
    }
}
__device__ inline void bfly16_inv(f2* M) {
    const float c8x[8]  = {1.f, TC1, TSQ, TS1, 0.f, -TS1, -TSQ, -TC1};
    const float c8y[8]  = {0.f, -TS1, -TSQ, -TC1, -1.f, -TC1, -TSQ, -TS1};
    const float c16x[4] = {1.f, TSQ, 0.f, -TSQ};
    const float c16y[4] = {0.f, -TSQ, -1.f, -TSQ};
    #pragma unroll
    for (int s = 0; s < 16; s += 2) {                // h=1
        f2 u0 = M[s], v0 = M[s + 1];
        M[s] = u0 + v0; M[s + 1] = u0 - v0;
    }
    #pragma unroll
    for (int q = 0; q < 8; ++q) {                    // h=2
        int s = (q & 1) + 4 * (q >> 1);
        f2 u0 = M[s];
        f2 v0 = M[s + 2];
        f2 vw = (s & 1) ? (f2){-v0.y, v0.x} : v0;    // conj(0,-1) = (0,1)
        M[s] = u0 + vw; M[s + 2] = u0 - vw;
    }
    #pragma unroll
    for (int q = 0; q < 8; ++q) {                    // h=4
        int s = (q & 3) + 8 * (q >> 2);
        f2 u0 = M[s];
        f2 vw = cmulcf(M[s + 4], (f2){c16x[s & 3], c16y[s & 3]});
        M[s] = u0 + vw; M[s + 4] = u0 - vw;
    }
    #pragma unroll
    for (int s = 0; s < 8; ++s) {                    // h=8
        f2 u0 = M[s];
        f2 vw = cmulcf(M[s + 8], (f2){c8x[s], c8y[s]});
        M[s] = u0 + vw; M[s + 8] = u0 - vw;
    }
}

__device__ inline void f_rowA(f2* Z, const f2* tw, int tid, int nrows, bool zup) {
    for (int u = tid; u < nrows * 16; u += 1024) {
        int r = u >> 4, b = u & 15;
        f2* row = Z + r * RS;
        f2 L[8];
        #pragma unroll
        for (int s = 0; s < 4; ++s) L[s] = row[17 * s + b];
        if (zup) {
            #pragma unroll
            for (int s = 4; s < 8; ++s) L[s] = (f2){0.f, 0.f};
        } else {
            #pragma unroll
            for (int s = 4; s < 8; ++s) L[s] = row[17 * s + b];
        }
        bflyA_fwd(L, tw, b);
        #pragma unroll
        for (int s = 0; s < 8; ++s) row[17 * s + b] = L[s];
    }
}
__device__ inline void f_rowB(f2* Z, int tid, int nrows) {
    for (int u = tid; u < nrows * 8; u += 1024) {
        int r = u >> 3, g = u & 7;
        f2* blk = Z + r * RS + g * 17;
        f2 M[16];
        #pragma unroll
        for (int s = 0; s < 16; ++s) M[s] = blk[s];
        bfly16_fwd(M);
        #pragma unroll
        for (int s = 0; s < 16; ++s) blk[s] = M[s];
    }
}
__device__ inline void f_colA(f2* Z, const f2* tw, int tid, bool zup) {
    for (int u = tid; u < 2048; u += 1024) {
        int c = u >> 4, b = u & 15;
        int cp = cpad(c);
        f2 L[8];
        #pragma unroll
        for (int s = 0; s < 4; ++s) L[s] = Z[(b + 16 * s) * RS + cp];
        if (zup) {
            #pragma unroll
            for (int s = 4; s < 8; ++s) L[s] = (f2){0.f, 0.f};
        } else {
            #pragma unroll
            for (int s = 4; s < 8; ++s) L[s] = Z[(b + 16 * s) * RS + cp];
        }
        bflyA_fwd(L, tw, b);
        #pragma unroll
        for (int s = 0; s < 8; ++s) Z[(b + 16 * s) * RS + cp] = L[s];
    }
}
// i_colA: only rows<64 of the output are consumed downstream -> store s<4.
__device__ inline void i_colA(f2* Z, const f2* tw, int tid) {
    for (int u = tid; u < 2048; u += 1024) {
        int c = u >> 4, b = u & 15;
        int cp = cpad(c);
        f2 L[8];
        #pragma unroll
        for (int s = 0; s < 8; ++s) L[s] = Z[(b + 16 * s) * RS + cp];
        bflyA_inv(L, tw, b);
        #pragma unroll
        for (int s = 0; s < 4; ++s) Z[(b + 16 * s) * RS + cp] = L[s];
    }
}
// colB: lanes span 64 columns (c = tid&127) so banks vary across a wave.
__device__ inline void f_colB(f2* Z, int tid) {        // setup
    int c = tid & 127, g = tid >> 7;
    f2* col = Z + g * 16 * RS + cpad(c);
    f2 M[16];
    #pragma unroll
    for (int s = 0; s < 16; ++s) M[s] = col[s * RS];
    bfly16_fwd(M);
    #pragma unroll
    for (int s = 0; s < 16; ++s) col[s * RS] = M[s];
}
// it_colB: Vf is REAL float (1/16384 pre-folded) — 16 real scales.
__device__ inline void it_colB(f2* Z, const float* Vfg, int tid) {
    int c = tid & 127, g = tid >> 7;
    f2* col = Z + g * 16 * RS + cpad(c);
    const float* vf = Vfg + g * 16 * 128 + c;
    f2 M[16];
    #pragma unroll
    for (int s = 0; s < 16; ++s) M[s] = col[s * RS];
    bfly16_fwd(M);
    #pragma unroll
    for (int s = 0; s < 16; ++s) M[s] = M[s] * f2s(vf[s * 128]);
    bfly16_inv(M);
    #pragma unroll
    for (int s = 0; s < 16; ++s) col[s * RS] = M[s];
}

// Reduce helpers: >=1 barrier separates reuses of the same buffer.
__device__ inline double blk_reduce_f(float v, double* red, int wid, int m) {
    #pragma unroll
    for (int off = 32; off > 0; off >>= 1) v += __shfl_down(v, off);
    if (m == 0) red[wid] = (double)v;
    __syncthreads();
    double s = 0.0;
    #pragma unroll
    for (int i = 0; i < 16; ++i) s += red[i];
    return s;
}

// ---------------------------------------------------------------------------
// k_cg_solve: R22 (6 barriers/iter via wave-synchronous row fusion).
// Thread tid owns elements e_s = (tid>>4)*64 + (tid&15) + 16s.
// Wave w (threads 64w..64w+63) owns rows 4w..4w+3:
//   rowA unit (r=tid>>4, b=tid&15); rowB/i_rowB unit for lane l<32:
//   r = 4w + (l>>3), g = l&7  — all producer/consumer pairs same-wave.
// ---------------------------------------------------------------------------
__global__ __launch_bounds__(1024, 4) void k_cg_solve(
        const float* __restrict__ vcf, float* __restrict__ Vf,
        const double2* __restrict__ rvec, const float* __restrict__ wsv,
        const float* __restrict__ sig2, float* __restrict__ alg)
{
    __shared__ f2 Z[128 * RS];
    __shared__ f2 tw[64];
    __shared__ double redA[16], redB[16], redC[16];

    int tid = threadIdx.x;
    int wid = tid >> 6, m = tid & 63;
    int rr_ = tid >> 4, bb_ = tid & 15;          // this thread's rowA unit
    int rB_ = (wid << 2) | (m >> 3), gB_ = m & 7; // wave-local rowB unit (m<32)

    if (tid < 64) {
        float sn, cs;
        sincospif(-(float)tid / 64.f, &sn, &cs);
        tw[tid] = (f2){cs, sn};
    }
    __syncthreads();

    // ---- Vf setup (forward transform of vc, scrambled order).
    //      Store REAL part only, scaled by 1/16384 (exact pow2).
    for (int i = tid; i < 16384; i += 1024)
        Z[(i >> 7) * RS + cpad(i & 127)] = ((const f2*)vcf)[i];
    __syncthreads();
    f_rowA(Z, tw, tid, 128, false); __syncthreads();
    f_rowB(Z, tid, 128);            __syncthreads();
    f_colA(Z, tw, tid, false);      __syncthreads();
    f_colB(Z, tid);                 __syncthreads();
    for (int i = tid; i < 16384; i += 1024)
        Vf[i] = Z[(i >> 7) * RS + cpad(i & 127)].x * (1.f / 16384.f);
    __syncthreads();

    // ---- CG state, fp32 (reference is complex64 end-to-end).
    f2 pR[4], rR[4], xR[4];
    float wsr[4];
    float rzp = 0.f;
    #pragma unroll
    for (int s = 0; s < 4; ++s) {
        int e = rr_ * 64 + bb_ + (s << 4);
        double2 bv = rvec[e];
        f2 bf = (f2){(float)bv.x, (float)bv.y};
        pR[s] = bf; rR[s] = bf;
        xR[s] = (f2){0.f, 0.f};
        wsr[s] = wsv[e];
        rzp += bf.x * bf.x + bf.y * bf.y;
    }
    double rz = blk_reduce_f(rzp, redC, wid, m);
    float s2f = sig2[0];
    __syncthreads();

    for (int it = 0; it < 50; ++it) {
        // ---- Phase 1 (fused, wave-sync): scatter+rowA, then rowB on the
        //      same wave's rows. Same-wave DS ops are in-order; no barrier.
        {
            f2* row = Z + rr_ * RS;
            f2 L[8];
            #pragma unroll
            for (int s = 0; s < 4; ++s) L[s] = f2s(wsr[s]) * pR[s];
            #pragma unroll
            for (int s = 4; s < 8; ++s) L[s] = (f2){0.f, 0.f};
            bflyA_fwd(L, tw, bb_);
            #pragma unroll
            for (int s = 0; s < 8; ++s) row[17 * s + bb_] = L[s];
        }
        __builtin_amdgcn_wave_barrier();     // compile-order fence (free)
        if (m < 32) {
            f2* blk = Z + rB_ * RS + gB_ * 17;
            f2 M[16];
            #pragma unroll
            for (int s = 0; s < 16; ++s) M[s] = blk[s];
            bfly16_fwd(M);
            #pragma unroll
            for (int s = 0; s < 16; ++s) blk[s] = M[s];
        }
        __syncthreads();

        f_colA(Z, tw, tid, true);                __syncthreads();
        it_colB(Z, Vf, tid);                     __syncthreads();
        i_colA(Z, tw, tid);                      __syncthreads();

        // ---- Phase 5 (fused, wave-sync): i_rowB on this wave's rows,
        //      then inverse rowA + Ap from the same wave's output.
        if (m < 32) {
            f2* blk = Z + rB_ * RS + gB_ * 17;
            f2 M[16];
            #pragma unroll
            for (int s = 0; s < 16; ++s) M[s] = blk[s];
            bfly16_inv(M);
            #pragma unroll
            for (int s = 0; s < 16; ++s) blk[s] = M[s];
        }
        __builtin_amdgcn_wave_barrier();     // compile-order fence (free)
        f2 ap[4];
        float papp = 0.f;
        {
            f2* row = Z + rr_ * RS;
            f2 L[8];
            #pragma unroll
            for (int s = 0; s < 8; ++s) L[s] = row[17 * s + bb_];
            bflyA_inv(L, tw, bb_);
            #pragma unroll
            for (int s = 0; s < 4; ++s) {
                ap[s].x = wsr[s] * L[s].x + s2f * pR[s].x;
                ap[s].y = wsr[s] * L[s].y + s2f * pR[s].y;
                papp += pR[s].x * ap[s].x + pR[s].y * ap[s].y;
            }
        }
        double pap = blk_reduce_f(papp, redA, wid, m);
        float alpha = (float)(rz / (pap + 1e-30));

        float rrp = 0.f;
        #pragma unroll
        for (int s = 0; s < 4; ++s) {
            xR[s] = xR[s] + f2s(alpha) * pR[s];
            rR[s] = rR[s] - f2s(alpha) * ap[s];
            rrp += rR[s].x * rR[s].x + rR[s].y * rR[s].y;
        }
        double rzn = blk_reduce_f(rrp, redB, wid, m);
        float beta = (float)(rzn / (rz + 1e-30));
        rz = rzn;
        #pragma unroll
        for (int s = 0; s < 4; ++s)
            pR[s] = rR[s] + f2s(beta) * pR[s];
    }

    // al = ws * x_50
    #pragma unroll
    for (int s = 0; s < 4; ++s) {
        int e = rr_ * 64 + bb_ + (s << 4);
        ((f2*)alg)[e] = f2s(wsr[s]) * xR[s];
    }
}

// ---------------------------------------------------------------------------
// k_eval: R20 — 256-thread blocks (shared al fill amortized 4x).
// R17 fp64 complex recurrences, 4 sincospi/thread.
// ---------------------------------------------------------------------------
__global__ __launch_bounds__(256) void k_eval(const float* __restrict__ xnew,
                                              const float* __restrict__ alg,
                                              float* __restrict__ out, int B)
{
    __shared__ float2 al[4096];
    int t = threadIdx.x;
    int b = blockIdx.x * 256 + t;
    for (int i = t; i < 4096; i += 256) {
        f2 v = ((const f2*)alg)[i];
        al[i] = make_float2(v.x, v.y);
    }
    float x0 = 0.f, x1 = 0.f;
    if (b < B) { x0 = xnew[2 * b]; x1 = xnew[2 * b + 1]; }
    __syncthreads();
    double2 wstep; { double sn, cs; sincospi((double)x1, &sn, &cs); wstep = make_double2(cs, sn); }
    double2 e2_0;  { double sn, cs; sincospi(-32.0 * (double)x1, &sn, &cs); e2_0 = make_double2(cs, sn); }
    double2 w1;    { double sn, cs; sincospi((double)x0, &sn, &cs); w1 = make_double2(cs, sn); }
    double2 e1;    { double sn, cs; sincospi(-32.0 * (double)x0, &sn, &cs); e1 = make_double2(cs, sn); }
    double mu = 0.0;
    for (int jg = 0; jg < 4; ++jg) {
        float2 tacc[16];
        for (int q = 0; q < 16; ++q) tacc[q] = make_float2(0.f, 0.f);
        double2 e2 = e2_0;
        for (int k = 0; k < 64; ++k) {
            float2 e2f = make_float2((float)e2.x, (float)e2.y);
            for (int q = 0; q < 16; ++q) {
                int j = jg * 16 + q;
                float2 a = al[j * 64 + k];
                tacc[q].x += a.x * e2f.x - a.y * e2f.y;
                tacc[q].y += a.x * e2f.y + a.y * e2f.x;
            }
            e2 = make_double2(e2.x * wstep.x - e2.y * wstep.y,
                              e2.x * wstep.y + e2.y * wstep.x);
        }
        for (int q = 0; q < 16; ++q) {
            mu += e1.x * (double)tacc[q].x - e1.y * (double)tacc[q].y;
            e1 = make_double2(e1.x * w1.x - e1.y * w1.y,
                              e1.x * w1.y + e1.y * w1.x);
        }
    }
    if (b < B) out[b] = (float)mu;
}

// ---------------------------------------------------------------------------

extern "C" void kernel_launch(void* const* d_in, const int* in_sizes, int n_in,
                              void* d_out, int out_size, void* d_ws, size_t ws_size,
                              hipStream_t stream)
{
    const float* x    = (const float*)d_in[0];
    const float* y    = (const float*)d_in[1];
    const float* xnew = (const float*)d_in[2];
    const float* wsv  = (const float*)d_in[3];
    const float* sig2 = (const float*)d_in[4];
    int N = in_sizes[1];
    int B = in_sizes[2] / 2;

    char* base = (char*)d_ws;
    size_t o = 0;
    float*   vcf  = (float*)(base + o);   o += 131072;   // 128x128 circulant vc (fp32)
    float*   Vf   = (float*)(base + o);   o += 65536;    // REAL FFT of vc, /16384 folded
    double2* rvec = (double2*)(base + o); o += 65536;    // b = ws*Fy (fp64)
    float*   alg  = (float*)(base + o);   o += 32768;    // ws*x_50 (fp32 complex)
    size_t avail = (ws_size > o) ? ws_size - o : 0;
    int cv = (int)(avail / 73728);                       // 64KB v-half + 8KB fy per unit
    if (cv > 768) cv = 768;
    if (cv < 16) cv = 16;
    cv &= ~15;
    int cf = cv / 4;
    float* pv = (float*)(base + o); o += (size_t)cv * 65536;
    float* pf = (float*)(base + o);

    hipMemsetAsync(vcf, 0, 131072, stream);              // fp32 atomic target

    k_outer<<<cv + cf, 256, 0, stream>>>(x, y, pv, pf, N, cv, cf);
    k_reduce<<<272, 256, 0, stream>>>(pv, pf, wsv, vcf, rvec, cv, cf);
    k_cg_solve<<<1, 1024, 0, stream>>>(vcf, Vf, rvec, wsv, sig2, alg);
    k_eval<<<(B + 255) / 256, 256, 0, stream>>>(xnew, alg, (float*)d_out, B);
}

// Round 10
// 946.149 us; speedup vs baseline: 1.0750x; 1.0750x over previous
//
#include <hip/hip_runtime.h>
#include <math.h>

// ---------------------------------------------------------------------------
// GP posterior mean:
//   k_outer : R18: half-grid v (conj-symmetric). R19: col-phase LDS layout
//     j-contiguous so h2 loads are 4xb128. launch_bounds (256,2) — R21/R22
//     A/B showed (256,4) neutral; keep verified config.
//   k_reduce: R21: exact grid (272 blocks) + explicit f-branch guard
//     (R18's unguarded else raced pv via OOB rvec writes).
//   k_cg_solve: R23 = R19-exact (541us verified, counter signature
//     FETCH~167K/WRITE~124K/conflicts 150336). Two structural edits to the
//     8-barrier schedule FAILED: R12 fused-reduce (+74us), R22 wave-sync
//     row fusion (+56us: intra-wave DS serial chain replaced cross-wave
//     overlap). This schedule is the verified optimum of its family.
//     R19: fp32 CG state. R17: Vf REAL fp32, 1/16384 folded. R16:
//     local-const bfly16 twiddles; i_colA half store. R14: CG-state remap
//     + fused scatter/rowA + i_rowA/Ap. R15: no register-array hoists.
//   k_eval  : R23 = R17-exact 64-thread blocks — R22 A/B showed 256-thread
//     blocks cost ~16us (79 blocks -> 79/256 CUs busy; latency-bound
//     kernel wants the 313-block spread).
// ---------------------------------------------------------------------------

typedef float f2 __attribute__((ext_vector_type(2)));
#define PB 16
#define RS 137          // Z row stride in f2 (8 blocks x 17)

__device__ inline f2 f2s(float s) { return (f2){s, s}; }
__device__ inline f2 cmulf(f2 a, f2 b) {   // a*b
    return (f2){a.x * b.x - a.y * b.y, a.x * b.y + a.y * b.x};
}
__device__ inline f2 cmulcf(f2 a, f2 b) {  // a*conj(b)
    return (f2){a.x * b.x + a.y * b.y, a.y * b.x - a.x * b.y};
}
__device__ inline int cpad(int c) { return (c >> 4) * 17 + (c & 15); }

// exp(i*pi*x*m) with fp64 angle reduction, scaled
__device__ inline f2 phasef(float xv, float m, float scale) {
    double ang = (double)xv * (double)m;
    double r = ang - 2.0 * rint(ang * 0.5);
    float sn, cs;
    sincospif((float)r, &sn, &cs);
    return (f2){cs * scale, sn * scale};
}

// ---------------------------------------------------------------------------
// k_outer: v-part computes HALF grid (rows p1=0..63, cols p2=-63..63).
// LDS layout: hs[p][0..63] = row phases (p1 = t).
//             hs[p][64 + 8*(cc&15) + (cc>>4)] = col phase cc (j-contiguous
//             per tx so h2 loads are 4xb128). cc=127 slot is zero.
// ---------------------------------------------------------------------------
__global__ __launch_bounds__(256, 2) void k_outer(const float* __restrict__ x,
                                                  const float* __restrict__ y,
                                                  float* __restrict__ pv,
                                                  float* __restrict__ pf,
                                                  int N, int cv, int cf)
{
    __shared__ f2 hs[PB][256];
    __shared__ float xs0[PB], xs1[PB], ys[PB];

    int bx = blockIdx.x;
    int t  = threadIdx.x;
    int ty = t >> 4, tx = t & 15;

    if (bx < cv) {
        int CP = (N + cv - 1) / cv;
        int n0 = bx * CP, n1 = min(N, n0 + CP);

        f2 acc[4][8];
        #pragma unroll
        for (int i = 0; i < 4; ++i)
            #pragma unroll
            for (int j = 0; j < 8; ++j) acc[i][j] = (f2){0.f, 0.f};

        for (int s = n0; s < n1; s += PB) {
            int cnt = min(PB, n1 - s);
            __syncthreads();
            if (t < cnt) {
                xs0[t] = x[2 * (s + t)];
                xs1[t] = x[2 * (s + t) + 1];
            }
            __syncthreads();
            for (int p = 0; p < cnt; ++p) {
                if (t < 192) {
                    if (t < 64) {
                        hs[p][t] = phasef(xs0[p], (float)t, 1.f);       // p1 = t
                    } else {
                        int cc = t - 64;                                 // 0..127
                        f2 g = (cc == 127) ? (f2){0.f, 0.f}
                                           : phasef(xs1[p], (float)(cc - 63), 1.f);
                        hs[p][64 + 8 * (cc & 15) + (cc >> 4)] = g;
                    }
                }
            }
            __syncthreads();
            for (int p = 0; p < cnt; ++p) {
                f2 h1[4], h2[8], h2s[8];
                #pragma unroll
                for (int i = 0; i < 4; ++i) h1[i] = hs[p][ty * 4 + i];
                #pragma unroll
                for (int j = 0; j < 8; ++j) {
                    f2 b = hs[p][64 + 8 * tx + j];                       // contiguous
                    h2[j] = b;
                    h2s[j] = (f2){-b.y, b.x};
                }
                #pragma unroll
                for (int i = 0; i < 4; ++i)
                    #pragma unroll
                    for (int j = 0; j < 8; ++j) {
                        acc[i][j] = acc[i][j] + f2s(h1[i].x) * h2[j];
                        acc[i][j] = acc[i][j] + f2s(h1[i].y) * h2s[j];
                    }
            }
        }
        __syncthreads();
        f2* out = (f2*)pv + (size_t)bx * 8192;           // 64x128 f2 = 64KB
        #pragma unroll
        for (int i = 0; i < 4; ++i) {
            int a = ty * 4 + i;
            #pragma unroll
            for (int j = 0; j < 8; ++j)
                out[a * 128 + tx + 16 * j] = acc[i][j];
        }
    } else {
        int chunk = bx - cv;
        int CP = (N + cf - 1) / cf;
        int n0 = chunk * CP, n1 = min(N, n0 + CP);

        f2 acc[4][4];
        #pragma unroll
        for (int i = 0; i < 4; ++i)
            #pragma unroll
            for (int j = 0; j < 4; ++j) acc[i][j] = (f2){0.f, 0.f};

        for (int s = n0; s < n1; s += PB) {
            int cnt = min(PB, n1 - s);
            __syncthreads();
            if (t < cnt) {
                xs0[t] = x[2 * (s + t)];
                xs1[t] = x[2 * (s + t) + 1];
                ys[t]  = y[s + t];
            }
            __syncthreads();
            for (int p2 = 0; p2 < cnt; p2 += 2) {
                int p = p2 + (t >> 7);
                int c = t & 127;
                if (p < cnt) {
                    f2 g;
                    if (c < 64) g = phasef(xs0[p], (float)(32 - c), ys[p]);
                    else        g = phasef(xs1[p], (float)(32 - (c - 64)), 1.f);
                    hs[p][c] = g;
                }
            }
            __syncthreads();
            for (int p = 0; p < cnt; ++p) {
                f2 h1[4], h2[4], h2s[4];
                #pragma unroll
                for (int i = 0; i < 4; ++i) h1[i] = hs[p][ty * 4 + i];
                #pragma unroll
                for (int j = 0; j < 4; ++j) {
                    f2 b = hs[p][64 + tx + 16 * j];
                    h2[j] = b;
                    h2s[j] = (f2){-b.y, b.x};
                }
                #pragma unroll
                for (int i = 0; i < 4; ++i)
                    #pragma unroll
                    for (int j = 0; j < 4; ++j) {
                        acc[i][j] = acc[i][j] + f2s(h1[i].x) * h2[j];
                        acc[i][j] = acc[i][j] + f2s(h1[i].y) * h2s[j];
                    }
            }
        }
        __syncthreads();
        f2* out = (f2*)pf + (size_t)chunk * 4096;
        #pragma unroll
        for (int i = 0; i < 4; ++i) {
            int a = ty * 4 + i;
            #pragma unroll
            for (int j = 0; j < 4; ++j)
                out[a * 64 + tx + 16 * j] = acc[i][j];
        }
    }
}

// ---------------------------------------------------------------------------
// k_reduce: R21. Grid sized EXACTLY: 65536 v-threads + 4096 f-threads =
// 69632 = 272 blocks, plus explicit guard.
//   direct: q1 = p1,        q2 = (b+65)&127,  value (sx,  sy)
//   mirror: q1 = 128-p1,    q2 = (63-b)&127,  value (sx, -sy)   [p1>0 only]
// ---------------------------------------------------------------------------
__global__ __launch_bounds__(256) void k_reduce(const float* __restrict__ pv,
                                                const float* __restrict__ pf,
                                                const float* __restrict__ wsv,
                                                float* __restrict__ vcf,
                                                double2* __restrict__ rvec,
                                                int cv, int cf)
{
    int id = blockIdx.x * 256 + threadIdx.x;
    if (id < 65536) {
        int e = id >> 3, sl = id & 7;        // e: p1 = e>>7 (0..63), b = e&127
        int cn = cv >> 3;
        const float* src = pv + (size_t)e * 2 + (size_t)(sl * cn) * 16384;
        float sx = 0.f, sy = 0.f;
        for (int c = 0; c < cn; ++c) { sx += src[0]; sy += src[1]; src += 16384; }
        int p1 = e >> 7, b = e & 127;
        int q2 = (b + 65) & 127;
        atomicAdd(&vcf[(p1 * 128 + q2) * 2],     sx);
        atomicAdd(&vcf[(p1 * 128 + q2) * 2 + 1], sy);
        if (p1 > 0) {
            int q1m = 128 - p1, q2m = (63 - b) & 127;
            atomicAdd(&vcf[(q1m * 128 + q2m) * 2],     sx);
            atomicAdd(&vcf[(q1m * 128 + q2m) * 2 + 1], -sy);
        }
    } else {
        int e = id - 65536;
        if (e < 4096) {                      // R21: explicit bound
            const float* s2p = pf + (size_t)e * 2;
            double fx = 0.0, fy2 = 0.0;
            for (int c = 0; c < cf; ++c) { fx += (double)s2p[0]; fy2 += (double)s2p[1]; s2p += 8192; }
            double w = (double)wsv[e];
            rvec[e] = make_double2(w * fx, w * fy2);
        }
    }
}

// ---------------------------------------------------------------------------
// Fused-stage FFT passes, STATIC register indexing only.
// Z[r*RS + cpad(c)], RS=137. tw[t] = exp(-i*pi*t/64) = W_128^t.
// bfly16 twiddles are lane-uniform -> LOCAL const tables (SROA-folded).
// ---------------------------------------------------------------------------
#define TC1 0.92387953251128676f   // cos(pi/8)
#define TS1 0.38268343236508977f   // sin(pi/8)
#define TSQ 0.70710678118654752f   // sqrt(2)/2

__device__ inline void bflyA_fwd(f2* L, const f2* tw, int b) {
    #pragma unroll
    for (int s = 0; s < 4; ++s) {                    // h=64
        f2 u0 = L[s], v0 = L[s + 4];
        L[s] = u0 + v0;
        L[s + 4] = cmulf(u0 - v0, tw[b + 16 * s]);
    }
    const int ss[4] = {0, 1, 4, 5};
    #pragma unroll
    for (int q = 0; q < 4; ++q) {                    // h=32
        int s = ss[q];
        f2 u0 = L[s], v0 = L[s + 2];
        L[s] = u0 + v0;
        L[s + 2] = cmulf(u0 - v0, tw[2 * b + 32 * (s & 1)]);
    }
    #pragma unroll
    for (int s = 0; s < 8; s += 2) {                 // h=16
        f2 u0 = L[s], v0 = L[s + 1];
        L[s] = u0 + v0;
        L[s + 1] = cmulf(u0 - v0, tw[4 * b]);
    }
}
__device__ inline void bflyA_inv(f2* L, const f2* tw, int b) {
    #pragma unroll
    for (int s = 0; s < 8; s += 2) {                 // h=16
        f2 u0 = L[s];
        f2 vw = cmulcf(L[s + 1], tw[4 * b]);
        L[s] = u0 + vw; L[s + 1] = u0 - vw;
    }
    const int ss[4] = {0, 1, 4, 5};
    #pragma unroll
    for (int q = 0; q < 4; ++q) {                    // h=32
        int s = ss[q];
        f2 u0 = L[s];
        f2 vw = cmulcf(L[s + 2], tw[2 * b + 32 * (s & 1)]);
        L[s] = u0 + vw; L[s + 2] = u0 - vw;
    }
    #pragma unroll
    for (int s = 0; s < 4; ++s) {                    // h=64
        f2 u0 = L[s];
        f2 vw = cmulcf(L[s + 4], tw[b + 16 * s]);
        L[s] = u0 + vw; L[s + 4] = u0 - vw;
    }
}
__device__ inline void bfly16_fwd(f2* M) {
    const float c8x[8]  = {1.f, TC1, TSQ, TS1, 0.f, -TS1, -TSQ, -TC1};
    const float c8y[8]  = {0.f, -TS1, -TSQ, -TC1, -1.f, -TC1, -TSQ, -TS1};
    const float c16x[4] = {1.f, TSQ, 0.f, -TSQ};
    const float c16y[4] = {0.f, -TSQ, -1.f, -TSQ};
    #pragma unroll
    for (int s = 0; s < 8; ++s) {                    // h=8
        f2 u0 = M[s], v0 = M[s + 8];
        M[s] = u0 + v0;
        M[s + 8] = cmulf(u0 - v0, (f2){c8x[s], c8y[s]});
    }
    #pragma unroll
    for (int q = 0; q < 8; ++q) {                    // h=4
        int s = (q & 3) + 8 * (q >> 2);
        f2 u0 = M[s], v0 = M[s + 4];
        M[s] = u0 + v0;
        M[s + 4] = cmulf(u0 - v0, (f2){c16x[s & 3], c16y[s & 3]});
    }
    #pragma unroll
    for (int q = 0; q < 8; ++q) {                    // h=2
        int s = (q & 1) + 4 * (q >> 1);
        f2 u0 = M[s], v0 = M[s + 2];
        M[s] = u0 + v0;
        f2 d = u0 - v0;
        M[s + 2] = (s & 1) ? (f2){d.y, -d.x} : d;    // * (0,-1) or * 1
    }
    #pragma unroll
    for (int s = 0; s < 16; s += 2) {                // h=1
        f2 u0 = M[s], v0 = M[s + 1];
        M[s] = u0 + v0; M[s + 1] = u0 - v0;
    }
}
__device__ inline void bfly16_inv(f2* M) {
    const float c8x[8]  = {1.f, TC1, TSQ, TS1, 0.f, -TS1, -TSQ, -TC1};
    const float c8y[8]  = {0.f, -TS1, -TSQ, -TC1, -1.f, -TC1, -TSQ, -TS1};
    const float c16x[4] = {1.f, TSQ, 0.f, -TSQ};
    const float c16y[4] = {0.f, -TSQ, -1.f, -TSQ};
    #pragma unroll
    for (int s = 0; s < 16; s += 2) {                // h=1
        f2 u0 = M[s], v0 = M[s + 1];
        M[s] = u0 + v0; M[s + 1] = u0 - v0;
    }
    #pragma unroll
    for (int q = 0; q < 8; ++q) {                    // h=2
        int s = (q & 1) + 4 * (q >> 1);
        f2 u0 = M[s];
        f2 v0 = M[s + 2];
        f2 vw = (s & 1) ? (f2){-v0.y, v0.x} : v0;    // conj(0,-1) = (0,1)
        M[s] = u0 + vw; M[s + 2] = u0 - vw;
    }
    #pragma unroll
    for (int q = 0; q < 8; ++q) {                    // h=4
        int s = (q & 3) + 8 * (q >> 2);
        f2 u0 = M[s];
        f2 vw = cmulcf(M[s + 4], (f2){c16x[s & 3], c16y[s & 3]});
        M[s] = u0 + vw; M[s + 4] = u0 - vw;
    }
    #pragma unroll
    for (int s = 0; s < 8; ++s) {                    // h=8
        f2 u0 = M[s];
        f2 vw = cmulcf(M[s + 8], (f2){c8x[s], c8y[s]});
        M[s] = u0 + vw; M[s + 8] = u0 - vw;
    }
}

__device__ inline void f_rowA(f2* Z, const f2* tw, int tid, int nrows, bool zup) {
    for (int u = tid; u < nrows * 16; u += 1024) {
        int r = u >> 4, b = u & 15;
        f2* row = Z + r * RS;
        f2 L[8];
        #pragma unroll
        for (int s = 0; s < 4; ++s) L[s] = row[17 * s + b];
        if (zup) {
            #pragma unroll
            for (int s = 4; s < 8; ++s) L[s] = (f2){0.f, 0.f};
        } else {
            #pragma unroll
            for (int s = 4; s < 8; ++s) L[s] = row[17 * s + b];
        }
        bflyA_fwd(L, tw, b);
        #pragma unroll
        for (int s = 0; s < 8; ++s) row[17 * s + b] = L[s];
    }
}
__device__ inline void f_rowB(f2* Z, int tid, int nrows) {
    for (int u = tid; u < nrows * 8; u += 1024) {
        int r = u >> 3, g = u & 7;
        f2* blk = Z + r * RS + g * 17;
        f2 M[16];
        #pragma unroll
        for (int s = 0; s < 16; ++s) M[s] = blk[s];
        bfly16_fwd(M);
        #pragma unroll
        for (int s = 0; s < 16; ++s) blk[s] = M[s];
    }
}
__device__ inline void i_rowB(f2* Z, int tid, int nrows) {
    for (int u = tid; u < nrows * 8; u += 1024) {
        int r = u >> 3, g = u & 7;
        f2* blk = Z + r * RS + g * 17;
        f2 M[16];
        #pragma unroll
        for (int s = 0; s < 16; ++s) M[s] = blk[s];
        bfly16_inv(M);
        #pragma unroll
        for (int s = 0; s < 16; ++s) blk[s] = M[s];
    }
}
__device__ inline void f_colA(f2* Z, const f2* tw, int tid, bool zup) {
    for (int u = tid; u < 2048; u += 1024) {
        int c = u >> 4, b = u & 15;
        int cp = cpad(c);
        f2 L[8];
        #pragma unroll
        for (int s = 0; s < 4; ++s) L[s] = Z[(b + 16 * s) * RS + cp];
        if (zup) {
            #pragma unroll
            for (int s = 4; s < 8; ++s) L[s] = (f2){0.f, 0.f};
        } else {
            #pragma unroll
            for (int s = 4; s < 8; ++s) L[s] = Z[(b + 16 * s) * RS + cp];
        }
        bflyA_fwd(L, tw, b);
        #pragma unroll
        for (int s = 0; s < 8; ++s) Z[(b + 16 * s) * RS + cp] = L[s];
    }
}
// i_colA: only rows<64 of the output are consumed downstream -> store s<4.
__device__ inline void i_colA(f2* Z, const f2* tw, int tid) {
    for (int u = tid; u < 2048; u += 1024) {
        int c = u >> 4, b = u & 15;
        int cp = cpad(c);
        f2 L[8];
        #pragma unroll
        for (int s = 0; s < 8; ++s) L[s] = Z[(b + 16 * s) * RS + cp];
        bflyA_inv(L, tw, b);
        #pragma unroll
        for (int s = 0; s < 4; ++s) Z[(b + 16 * s) * RS + cp] = L[s];
    }
}
// colB: lanes span 64 columns (c = tid&127) so banks vary across a wave.
__device__ inline void f_colB(f2* Z, int tid) {        // setup
    int c = tid & 127, g = tid >> 7;
    f2* col = Z + g * 16 * RS + cpad(c);
    f2 M[16];
    #pragma unroll
    for (int s = 0; s < 16; ++s) M[s] = col[s * RS];
    bfly16_fwd(M);
    #pragma unroll
    for (int s = 0; s < 16; ++s) col[s * RS] = M[s];
}
// it_colB: Vf is REAL float (1/16384 pre-folded) — 16 real scales.
__device__ inline void it_colB(f2* Z, const float* Vfg, int tid) {
    int c = tid & 127, g = tid >> 7;
    f2* col = Z + g * 16 * RS + cpad(c);
    const float* vf = Vfg + g * 16 * 128 + c;
    f2 M[16];
    #pragma unroll
    for (int s = 0; s < 16; ++s) M[s] = col[s * RS];
    bfly16_fwd(M);
    #pragma unroll
    for (int s = 0; s < 16; ++s) M[s] = M[s] * f2s(vf[s * 128]);
    bfly16_inv(M);
    #pragma unroll
    for (int s = 0; s < 16; ++s) col[s * RS] = M[s];
}

// Reduce helpers: >=1 barrier separates reuses of the same buffer.
__device__ inline double blk_reduce_f(float v, double* red, int wid, int m) {
    #pragma unroll
    for (int off = 32; off > 0; off >>= 1) v += __shfl_down(v, off);
    if (m == 0) red[wid] = (double)v;
    __syncthreads();
    double s = 0.0;
    #pragma unroll
    for (int i = 0; i < 16; ++i) s += red[i];
    return s;
}

// ---------------------------------------------------------------------------
// k_cg_solve: R19-exact (fp32 CG state, 8 barriers/iter). Thread tid owns
// elements e_s = (tid>>4)*64 + (tid&15) + 16s.
// ---------------------------------------------------------------------------
__global__ __launch_bounds__(1024, 4) void k_cg_solve(
        const float* __restrict__ vcf, float* __restrict__ Vf,
        const double2* __restrict__ rvec, const float* __restrict__ wsv,
        const float* __restrict__ sig2, float* __restrict__ alg)
{
    __shared__ f2 Z[128 * RS];
    __shared__ f2 tw[64];
    __shared__ double redA[16], redB[16], redC[16];

    int tid = threadIdx.x;
    int wid = tid >> 6, m = tid & 63;
    int rr_ = tid >> 4, bb_ = tid & 15;          // this thread's rowA unit

    if (tid < 64) {
        float sn, cs;
        sincospif(-(float)tid / 64.f, &sn, &cs);
        tw[tid] = (f2){cs, sn};
    }
    __syncthreads();

    // ---- Vf setup (forward transform of vc, scrambled order).
    //      Store REAL part only, scaled by 1/16384 (exact pow2).
    for (int i = tid; i < 16384; i += 1024)
        Z[(i >> 7) * RS + cpad(i & 127)] = ((const f2*)vcf)[i];
    __syncthreads();
    f_rowA(Z, tw, tid, 128, false); __syncthreads();
    f_rowB(Z, tid, 128);            __syncthreads();
    f_colA(Z, tw, tid, false);      __syncthreads();
    f_colB(Z, tid);                 __syncthreads();
    for (int i = tid; i < 16384; i += 1024)
        Vf[i] = Z[(i >> 7) * RS + cpad(i & 127)].x * (1.f / 16384.f);
    __syncthreads();

    // ---- CG state, fp32 (reference is complex64 end-to-end).
    f2 pR[4], rR[4], xR[4];
    float wsr[4];
    float rzp = 0.f;
    #pragma unroll
    for (int s = 0; s < 4; ++s) {
        int e = rr_ * 64 + bb_ + (s << 4);
        double2 bv = rvec[e];
        f2 bf = (f2){(float)bv.x, (float)bv.y};
        pR[s] = bf; rR[s] = bf;
        xR[s] = (f2){0.f, 0.f};
        wsr[s] = wsv[e];
        rzp += bf.x * bf.x + bf.y * bf.y;
    }
    double rz = blk_reduce_f(rzp, redC, wid, m);
    float s2f = sig2[0];
    __syncthreads();

    for (int it = 0; it < 50; ++it) {
        // ---- fused scatter + forward rowA: z = ws*p from regs (zero-padded)
        {
            f2* row = Z + rr_ * RS;
            f2 L[8];
            #pragma unroll
            for (int s = 0; s < 4; ++s) L[s] = f2s(wsr[s]) * pR[s];
            #pragma unroll
            for (int s = 4; s < 8; ++s) L[s] = (f2){0.f, 0.f};
            bflyA_fwd(L, tw, bb_);
            #pragma unroll
            for (int s = 0; s < 8; ++s) row[17 * s + bb_] = L[s];
        }
        __syncthreads();

        f_rowB(Z, tid, 64);                      __syncthreads();
        f_colA(Z, tw, tid, true);                __syncthreads();
        it_colB(Z, Vf, tid);                     __syncthreads();
        i_colA(Z, tw, tid);                      __syncthreads();
        i_rowB(Z, tid, 64);                      __syncthreads();

        // ---- fused inverse rowA + Ap (az pre-scaled by 1/16384 via Vf)
        f2 ap[4];
        float papp = 0.f;
        {
            f2* row = Z + rr_ * RS;
            f2 L[8];
            #pragma unroll
            for (int s = 0; s < 8; ++s) L[s] = row[17 * s + bb_];
            bflyA_inv(L, tw, bb_);
            #pragma unroll
            for (int s = 0; s < 4; ++s) {
                ap[s].x = wsr[s] * L[s].x + s2f * pR[s].x;
                ap[s].y = wsr[s] * L[s].y + s2f * pR[s].y;
                papp += pR[s].x * ap[s].x + pR[s].y * ap[s].y;
            }
        }
        double pap = blk_reduce_f(papp, redA, wid, m);
        float alpha = (float)(rz / (pap + 1e-30));

        float rrp = 0.f;
        #pragma unroll
        for (int s = 0; s < 4; ++s) {
            xR[s] = xR[s] + f2s(alpha) * pR[s];
            rR[s] = rR[s] - f2s(alpha) * ap[s];
            rrp += rR[s].x * rR[s].x + rR[s].y * rR[s].y;
        }
        double rzn = blk_reduce_f(rrp, redB, wid, m);
        float beta = (float)(rzn / (rz + 1e-30));
        rz = rzn;
        #pragma unroll
        for (int s = 0; s < 4; ++s)
            pR[s] = rR[s] + f2s(beta) * pR[s];
    }

    // al = ws * x_50
    #pragma unroll
    for (int s = 0; s < 4; ++s) {
        int e = rr_ * 64 + bb_ + (s << 4);
        ((f2*)alg)[e] = f2s(wsr[s]) * xR[s];
    }
}

// ---------------------------------------------------------------------------
// k_eval: R17-exact — 64-thread blocks (313 blocks spread over 256 CUs;
// latency-bound). fp64 complex recurrences, 4 sincospi/thread.
// ---------------------------------------------------------------------------
__global__ __launch_bounds__(64) void k_eval(const float* __restrict__ xnew,
                                             const float* __restrict__ alg,
                                             float* __restrict__ out, int B)
{
    __shared__ float2 al[4096];
    int t = threadIdx.x;
    int b = blockIdx.x * 64 + t;
    for (int i = t; i < 4096; i += 64) {
        f2 v = ((const f2*)alg)[i];
        al[i] = make_float2(v.x, v.y);
    }
    float x0 = 0.f, x1 = 0.f;
    if (b < B) { x0 = xnew[2 * b]; x1 = xnew[2 * b + 1]; }
    __syncthreads();
    double2 wstep; { double sn, cs; sincospi((double)x1, &sn, &cs); wstep = make_double2(cs, sn); }
    double2 e2_0;  { double sn, cs; sincospi(-32.0 * (double)x1, &sn, &cs); e2_0 = make_double2(cs, sn); }
    double2 w1;    { double sn, cs; sincospi((double)x0, &sn, &cs); w1 = make_double2(cs, sn); }
    double2 e1;    { double sn, cs; sincospi(-32.0 * (double)x0, &sn, &cs); e1 = make_double2(cs, sn); }
    double mu = 0.0;
    for (int jg = 0; jg < 4; ++jg) {
        float2 tacc[16];
        for (int q = 0; q < 16; ++q) tacc[q] = make_float2(0.f, 0.f);
        double2 e2 = e2_0;
        for (int k = 0; k < 64; ++k) {
            float2 e2f = make_float2((float)e2.x, (float)e2.y);
            for (int q = 0; q < 16; ++q) {
                int j = jg * 16 + q;
                float2 a = al[j * 64 + k];
                tacc[q].x += a.x * e2f.x - a.y * e2f.y;
                tacc[q].y += a.x * e2f.y + a.y * e2f.x;
            }
            e2 = make_double2(e2.x * wstep.x - e2.y * wstep.y,
                              e2.x * wstep.y + e2.y * wstep.x);
        }
        for (int q = 0; q < 16; ++q) {
            mu += e1.x * (double)tacc[q].x - e1.y * (double)tacc[q].y;
            e1 = make_double2(e1.x * w1.x - e1.y * w1.y,
                              e1.x * w1.y + e1.y * w1.x);
        }
    }
    if (b < B) out[b] = (float)mu;
}

// ---------------------------------------------------------------------------

extern "C" void kernel_launch(void* const* d_in, const int* in_sizes, int n_in,
                              void* d_out, int out_size, void* d_ws, size_t ws_size,
                              hipStream_t stream)
{
    const float* x    = (const float*)d_in[0];
    const float* y    = (const float*)d_in[1];
    const float* xnew = (const float*)d_in[2];
    const float* wsv  = (const float*)d_in[3];
    const float* sig2 = (const float*)d_in[4];
    int N = in_sizes[1];
    int B = in_sizes[2] / 2;

    char* base = (char*)d_ws;
    size_t o = 0;
    float*   vcf  = (float*)(base + o);   o += 131072;   // 128x128 circulant vc (fp32)
    float*   Vf   = (float*)(base + o);   o += 65536;    // REAL FFT of vc, /16384 folded
    double2* rvec = (double2*)(base + o); o += 65536;    // b = ws*Fy (fp64)
    float*   alg  = (float*)(base + o);   o += 32768;    // ws*x_50 (fp32 complex)
    size_t avail = (ws_size > o) ? ws_size - o : 0;
    int cv = (int)(avail / 73728);                       // 64KB v-half + 8KB fy per unit
    if (cv > 768) cv = 768;
    if (cv < 16) cv = 16;
    cv &= ~15;
    int cf = cv / 4;
    float* pv = (float*)(base + o); o += (size_t)cv * 65536;
    float* pf = (float*)(base + o);

    hipMemsetAsync(vcf, 0, 131072, stream);              // fp32 atomic target

    k_outer<<<cv + cf, 256, 0, stream>>>(x, y, pv, pf, N, cv, cf);
    k_reduce<<<272, 256, 0, stream>>>(pv, pf, wsv, vcf, rvec, cv, cf);
    k_cg_solve<<<1, 1024, 0, stream>>>(vcf, Vf, rvec, wsv, sig2, alg);
    k_eval<<<(B + 63) / 64, 64, 0, stream>>>(xnew, alg, (float*)d_out, B);
}